// Round 2
// baseline (192.961 us; speedup 1.0000x reference)
//
#include <hip/hip_runtime.h>
#include <hip/hip_bf16.h>

// Problem constants
#define BB 16
#define TT 2048
#define CC 128
#define HH 128
#define NQT128 16          // q tiles of 128 rows

typedef __bf16 bf16x8 __attribute__((ext_vector_type(8)));
typedef __bf16 bf16x4 __attribute__((ext_vector_type(4)));
typedef float  f32x4  __attribute__((ext_vector_type(4)));

// ws layout (bf16 elems unless noted):
//   Qs  [b][tt16 128][ks 4][lane 64][j 8]   (exp2-domain scale folded)
//   Ks  [b][tt16 128][ks 4][lane 64][j 8]   (32-key tile = 8 KB contig)
//   Vs  [b][t32 64][h16 8][lane 64][j 8]    (32-key tile = 8 KB contig)
//   Wbf 3*128*128 FRAGMENT-SWIZZLED: [which][blk16 8][ks 4][lane 64][j 8]
//   partial slots: bf16 o[128*128] (32768 B) + float l[128] (512 B)
#define BTH       ((size_t)BB * TT * HH)
#define WBF_OFF   (3 * BTH)
#define PARTIAL_OFF_BYTES (3 * BTH * 2 + 3 * 128 * 128 * 2)
#define SLOT_BYTES 33280
#define SLOT_L_OFF 32768

static __device__ __forceinline__ bf16x8 load_cvt8(const float* p) {
    float4 a = *(const float4*)p;
    float4 b = *(const float4*)(p + 4);
    bf16x8 r;
    r[0] = (__bf16)a.x; r[1] = (__bf16)a.y; r[2] = (__bf16)a.z; r[3] = (__bf16)a.w;
    r[4] = (__bf16)b.x; r[5] = (__bf16)b.y; r[6] = (__bf16)b.z; r[7] = (__bf16)b.w;
    return r;
}

// async global->LDS, 16 B/lane: data lands at lds_base + lane*16
static __device__ __forceinline__ void load_lds16(const void* g, void* l) {
    __builtin_amdgcn_global_load_lds(
        (const __attribute__((address_space(1))) unsigned int*)g,
        (__attribute__((address_space(3))) unsigned int*)l, 16, 0, 0);
}

#define BAR_LGKM() asm volatile("s_waitcnt lgkmcnt(0)\n\ts_barrier" ::: "memory")

// ---------------------------------------------------------------------------
// W pre-convert + FRAGMENT SWIZZLE (proj W loads become lane*16B coalesced).
// ---------------------------------------------------------------------------
__global__ __launch_bounds__(256) void wcvt_kernel(
    const float* __restrict__ Wq, const float* __restrict__ Wk,
    const float* __restrict__ Wv, __bf16* __restrict__ wbf)
{
    int idx = blockIdx.x * 256 + threadIdx.x;          // < 6144
    int which = idx >> 11;
    int rem = idx & 2047;
    int blk = rem >> 8;
    int r2  = rem & 255;
    int ks   = r2 >> 6;
    int lane = r2 & 63;
    int quad = lane >> 4, l16 = lane & 15;
    const float* src = (which == 0) ? Wq : (which == 1) ? Wk : Wv;
    float sc = (which == 0) ? (0.08838834764831845f * 1.4426950408889634f) : 1.0f;
    const float* p = src + (size_t)(blk * 16 + l16) * CC + ks * 32 + quad * 8;
    bf16x8 v;
    #pragma unroll
    for (int j = 0; j < 8; ++j) v[j] = (__bf16)(p[j] * sc);
    *(bf16x8*)(wbf + (size_t)which * 16384 + (((size_t)(blk * 4 + ks)) << 9) + lane * 8) = v;
}

// ---------------------------------------------------------------------------
// Projection, fully coalesced (x via padded LDS, W fragment-swizzled).
// ---------------------------------------------------------------------------
#define TR_QK 132
#define TR_V  68

__global__ __launch_bounds__(256) void proj_kernel(
    const float* __restrict__ x, __bf16* __restrict__ ws)
{
    __shared__ float  xs[64 * 132];
    __shared__ __bf16 tr[128 * TR_V];

    const int lane = threadIdx.x & 63;
    const int wave = threadIdx.x >> 6;
    const int quad = lane >> 4;
    const int l16  = lane & 15;
    const int tid  = threadIdx.x;
    const int m0 = blockIdx.x * 64;
    const int b  = m0 / TT;
    const int t0 = m0 % TT;

    const __bf16* Wbf = ws + WBF_OFF;
    __bf16* Qs = ws;
    __bf16* Ks = ws + BTH;
    __bf16* Vs = ws + 2 * BTH;

    const float* xg = x + (size_t)m0 * CC;
    #pragma unroll
    for (int t = 0; t < 8; ++t) {
        int f = t * 256 + tid;
        int row = f >> 5, c4 = f & 31;
        float4 v = *(const float4*)(xg + (size_t)f * 4);
        *(float4*)(&xs[row * 132 + c4 * 4]) = v;
    }
    __syncthreads();

    bf16x8 xf[4];
    #pragma unroll
    for (int ks = 0; ks < 4; ++ks)
        xf[ks] = load_cvt8(&xs[(wave * 16 + l16) * 132 + ks * 32 + quad * 8]);

    #pragma unroll
    for (int which = 0; which < 2; ++which) {
        const __bf16* Wb = Wbf + (size_t)which * 16384;
        __bf16* dst = which ? Ks : Qs;
        #pragma unroll
        for (int nt = 0; nt < 8; ++nt) {
            f32x4 acc = {0.f, 0.f, 0.f, 0.f};
            #pragma unroll
            for (int ks = 0; ks < 4; ++ks) {
                bf16x8 wf = *(const bf16x8*)(Wb + (((size_t)(nt * 4 + ks)) << 9) + lane * 8);
                acc = __builtin_amdgcn_mfma_f32_16x16x32_bf16(xf[ks], wf, acc, 0, 0, 0);
            }
            #pragma unroll
            for (int r = 0; r < 4; ++r)
                tr[(wave * 16 + quad * 4 + r) * TR_QK + nt * 16 + l16] = (__bf16)acc[r];
        }
        asm volatile("s_waitcnt lgkmcnt(0)" ::: "memory");
        #pragma unroll
        for (int ks = 0; ks < 4; ++ks) {
            const __bf16* p = &tr[(wave * 16 + l16) * TR_QK + ks * 32 + quad * 8];
            uint2 lo = *(const uint2*)p;
            uint2 hi = *(const uint2*)(p + 4);
            uint4 v; v.x = lo.x; v.y = lo.y; v.z = hi.x; v.w = hi.y;
            __bf16* o = dst + (((size_t)(b * 128 + t0 / 16 + wave) * 4 + ks) << 9) + lane * 8;
            *(uint4*)o = v;
        }
        asm volatile("s_waitcnt lgkmcnt(0)" ::: "memory");
    }

    __syncthreads();
    const __bf16* Wv = Wbf + 2 * 16384;
    #pragma unroll
    for (int msub = 0; msub < 8; ++msub) {
        f32x4 acc = {0.f, 0.f, 0.f, 0.f};
        #pragma unroll
        for (int ks = 0; ks < 4; ++ks) {
            bf16x8 wf = *(const bf16x8*)(Wv + (((size_t)(msub * 4 + ks)) << 9) + lane * 8);
            acc = __builtin_amdgcn_mfma_f32_16x16x32_bf16(wf, xf[ks], acc, 0, 0, 0);
        }
        #pragma unroll
        for (int r = 0; r < 4; ++r)
            tr[(msub * 16 + quad * 4 + r) * TR_V + wave * 16 + l16] = (__bf16)acc[r];
    }
    __syncthreads();
    #pragma unroll
    for (int i = 0; i < 4; ++i) {
        int t32 = i >> 1;
        int h16 = wave * 2 + (i & 1);
        const __bf16* p = &tr[(h16 * 16 + l16) * TR_V + t32 * 32 + quad * 8];
        uint2 lo = *(const uint2*)p;
        uint2 hi = *(const uint2*)(p + 4);
        uint4 v; v.x = lo.x; v.y = lo.y; v.z = hi.x; v.w = hi.y;
        __bf16* o = Vs + (((size_t)(b * 64 + t0 / 32 + t32) * 8 + h16) << 9) + lane * 8;
        *(uint4*)o = v;
    }
}

// ---------------------------------------------------------------------------
// Split-K flash attention, 32-key tiles, double-buffered LDS staging.
//  - swapped QK^T (mfma(K,Q) -> S^T): P spill = 4x ds_write_b64 (packed),
//    XOR-swizzled 64B P rows; P reload stays 2x ds_read_b128.
//  - counted vmcnt(4): next-tile DMA issued BEFORE the barrier, never drained
//    to 0 mid-loop (stage(t)'s 4 loads are oldest of exactly 8 outstanding).
//  - V fragments prefetched to registers under the exp2 phase.
//  - LDS exactly 40960 B -> 4 blocks/CU (16 waves/CU vs 12 before).
//  - incremental 8KB-contiguous stage pointers; unroll-by-2 over buffers
//    (segment length in 32-key tiles is always even).
// ---------------------------------------------------------------------------
__global__ __launch_bounds__(256, 4) void attn_kernel(
    const __bf16* __restrict__ ws, char* __restrict__ po,
    float* __restrict__ outp, int G, int SPB, int direct)
{
    __shared__ __bf16 ldsK[2][4096];            // 2 x 8 KB
    __shared__ __bf16 ldsV[2][4096];            // 2 x 8 KB
    __shared__ __bf16 lds_p[4096];              // 8 KB -> total 40960 B

    const int lane = threadIdx.x & 63;
    const int wave = threadIdx.x >> 6;
    const int quad = lane >> 4;
    const int l16  = lane & 15;
    const int lane8 = lane * 8;
    const int lo16 = lane * 16;

    const int lin = blockIdx.x;
    const int b  = (lin & 7) * 2 + ((lin >> 3) & 1);   // XCD-clustered batch
    const int s  = SPB - 1 - (lin >> 4);               // heavy slots first

    // slot -> (qt, seg) in 64-key units, then convert to 32-key tiles
    int acc = 0, qt = 0, seg = 0;
    for (int q = 0; q < NQT128; ++q) {
        int c = (2 * (q + 1) + G - 1) / G;
        if (s < acc + c) { qt = q; seg = s - acc; break; }
        acc += c;
    }
    const int kt0 = seg * G;
    int kt1 = 2 * (qt + 1);
    if (kt0 + G < kt1) kt1 = kt0 + G;
    const int segs_qt = (2 * (qt + 1) + G - 1) / G;
    const int dwrite = direct | (segs_qt == 1);

    const int tt0 = kt0 * 2, tt1 = kt1 * 2;            // 32-key tiles (even count)
    const int qw = qt * 128 + wave * 32;               // wave's first q row
    int ttw = (qw + 63) >> 5;                          // wave causal clamp
    if (ttw > tt1) ttw = tt1;

    const __bf16* Qs = ws;
    const __bf16* Ks = ws + BTH;
    const __bf16* Vs = ws + 2 * BTH;

    bf16x8 qf[2][4];
    #pragma unroll
    for (int m = 0; m < 2; ++m)
        #pragma unroll
        for (int ks = 0; ks < 4; ++ks)
            qf[m][ks] = *(const bf16x8*)(Qs + (((size_t)(b * 128 + qt * 8 + wave * 2 + m) * 4 + ks) << 9) + lane8);

    float l_r[2] = {0.f, 0.f};
    f32x4 o[2][8];
    #pragma unroll
    for (int m = 0; m < 2; ++m)
        #pragma unroll
        for (int h8 = 0; h8 < 8; ++h8) o[m][h8] = (f32x4){0.f, 0.f, 0.f, 0.f};

    char* myP = (char*)lds_p + wave * 2048;            // 2 m x 16 rows x 64 B

    // incremental staging pointers: each 32-key tile is 8 KB contiguous
    const char* kg = (const char*)Ks + (size_t)b * 524288 + wave * 2048 + lo16;
    const char* vg = (const char*)Vs + (size_t)b * 524288 + wave * 2048 + lo16;
    char* const dKa[2] = {(char*)ldsK[0] + wave * 2048, (char*)ldsK[1] + wave * 2048};
    char* const dVa[2] = {(char*)ldsV[0] + wave * 2048, (char*)ldsV[1] + wave * 2048};

    #define STAGE(TTv, KD, VD)                                  \
        do {                                                    \
            size_t o_ = (size_t)(TTv) << 13;                    \
            load_lds16(kg + o_,        (KD));                   \
            load_lds16(kg + o_ + 1024, (KD) + 1024);            \
            load_lds16(vg + o_,        (VD));                   \
            load_lds16(vg + o_ + 1024, (VD) + 1024);            \
        } while (0)

    STAGE(tt0, dKa[0], dVa[0]);

    for (int tp = tt0; tp < tt1; tp += 2) {
        #pragma unroll
        for (int hh = 0; hh < 2; ++hh) {
            const int tt = tp + hh;
            // issue next-tile DMA before the barrier; counted wait keeps it in flight
            if (tt + 1 < tt1) {
                STAGE(tt + 1, dKa[hh ^ 1], dVa[hh ^ 1]);
                asm volatile("s_waitcnt vmcnt(4)" ::: "memory");
            } else {
                asm volatile("s_waitcnt vmcnt(0)" ::: "memory");
            }
            __builtin_amdgcn_s_barrier();

            if (tt < ttw) {
                const char* lk = (const char*)ldsK[hh];
                const char* lv = (const char*)ldsV[hh];

                // ---- S^T = K Q^T (swapped: lane holds 4 consecutive keys / q) --
                f32x4 s2[2][2];
                #pragma unroll
                for (int nsub = 0; nsub < 2; ++nsub) {
                    bf16x8 kfr[4];
                    #pragma unroll
                    for (int ks = 0; ks < 4; ++ks)
                        kfr[ks] = *(const bf16x8*)(lk + ((nsub * 4 + ks) << 10) + lo16);
                    #pragma unroll
                    for (int m = 0; m < 2; ++m) {
                        f32x4 a2 = {0.f, 0.f, 0.f, 0.f};
                        #pragma unroll
                        for (int ks = 0; ks < 4; ++ks)
                            a2 = __builtin_amdgcn_mfma_f32_16x16x32_bf16(kfr[ks], qf[m][ks], a2, 0, 0, 0);
                        s2[m][nsub] = a2;
                    }
                }

                // ---- V fragment prefetch (latency hides under exp2 phase) ----
                bf16x8 vr[8];
                #pragma unroll
                for (int h8 = 0; h8 < 8; ++h8)
                    vr[h8] = *(const bf16x8*)(lv + (h8 << 10) + lo16);

                const int k0 = tt * 32;
                // ---- mask + exp2 + lane-local l + packed b64 P write ---------
                #pragma unroll
                for (int m = 0; m < 2; ++m) {
                    const int qrow = qw + m * 16 + l16;     // this lane's q row
                    char* rowp = myP + m * 1024 + l16 * 64;
                    const int swz = (l16 & 3) << 4;
                    if (k0 + 31 > qw + m * 16) {            // boundary tile (uniform)
                        #pragma unroll
                        for (int nsub = 0; nsub < 2; ++nsub) {
                            const int kb = k0 + nsub * 16 + quad * 4;
                            bf16x4 pw;
                            #pragma unroll
                            for (int r = 0; r < 4; ++r) {
                                float sv = (kb + r > qrow) ? -3e38f : s2[m][nsub][r];
                                float p = __builtin_amdgcn_exp2f(sv);
                                l_r[m] += p;
                                pw[r] = (__bf16)p;
                            }
                            *(bf16x4*)(rowp + ((nsub * 32 + quad * 8) ^ swz)) = pw;
                        }
                    } else {
                        #pragma unroll
                        for (int nsub = 0; nsub < 2; ++nsub) {
                            bf16x4 pw;
                            #pragma unroll
                            for (int r = 0; r < 4; ++r) {
                                float p = __builtin_amdgcn_exp2f(s2[m][nsub][r]);
                                l_r[m] += p;
                                pw[r] = (__bf16)p;
                            }
                            *(bf16x4*)(rowp + ((nsub * 32 + quad * 8) ^ swz)) = pw;
                        }
                    }
                }
                asm volatile("s_waitcnt lgkmcnt(0)" ::: "memory");

                // ---- P reload in A-layout (one b128 per m, swizzled) ---------
                bf16x8 pf[2];
                #pragma unroll
                for (int m = 0; m < 2; ++m)
                    pf[m] = *(const bf16x8*)(myP + m * 1024 + l16 * 64 + ((quad * 16) ^ ((l16 & 3) << 4)));

                // ---- O += P V (k = 32) ---------------------------------------
                #pragma unroll
                for (int h8 = 0; h8 < 8; ++h8)
                    #pragma unroll
                    for (int m = 0; m < 2; ++m)
                        o[m][h8] = __builtin_amdgcn_mfma_f32_16x16x32_bf16(pf[m], vr[h8], o[m][h8], 0, 0, 0);
            }
            BAR_LGKM();    // all waves' LDS reads of buf hh complete before reuse
        }
    }
    #undef STAGE

    // l reduction across quads (lane holds full row-sum for q = l16-row after)
    #pragma unroll
    for (int m = 0; m < 2; ++m) {
        l_r[m] += __shfl_xor(l_r[m], 16, 64);
        l_r[m] += __shfl_xor(l_r[m], 32, 64);
    }

    if (dwrite) {
        #pragma unroll
        for (int m = 0; m < 2; ++m) {
            float inv[4];
            #pragma unroll
            for (int r = 0; r < 4; ++r)
                inv[r] = 1.0f / __shfl(l_r[m], (lane & 48) | (quad * 4 + r), 64);
            #pragma unroll
            for (int h8 = 0; h8 < 8; ++h8)
                #pragma unroll
                for (int r = 0; r < 4; ++r)
                    outp[(size_t)(b * TT + qw + m * 16 + quad * 4 + r) * HH + h8 * 16 + l16] = o[m][h8][r] * inv[r];
        }
    } else {
        char* slot = po + (size_t)(b * SPB + s) * SLOT_BYTES;
        __bf16* slot_o = (__bf16*)slot;
        float*  slot_l = (float*)(slot + SLOT_L_OFF);
        #pragma unroll
        for (int m = 0; m < 2; ++m) {
            #pragma unroll
            for (int h8 = 0; h8 < 8; ++h8)
                #pragma unroll
                for (int r = 0; r < 4; ++r)
                    slot_o[(size_t)(wave * 32 + m * 16 + quad * 4 + r) * 128 + h8 * 16 + l16] = (__bf16)o[m][h8][r];
            if (quad == 0)
                slot_l[wave * 32 + m * 16 + l16] = l_r[m];
        }
    }
}

// ---------------------------------------------------------------------------
// Reduce: sum bf16 partial o + fp32 l over segments, normalize.
// ---------------------------------------------------------------------------
__global__ __launch_bounds__(256) void reduce_kernel(
    const char* __restrict__ po, float* __restrict__ outp, int G, int SPB)
{
    __shared__ float lsum[32];
    const int qt  = blockIdx.x >> 2;
    const int qtr = blockIdx.x & 3;
    const int b   = blockIdx.y;
    const int tid = threadIdx.x;

    const int segs = (2 * (qt + 1) + G - 1) / G;
    if (segs == 1) return;

    int acc = 0;
    for (int qq = 0; qq < qt; ++qq) acc += (2 * (qq + 1) + G - 1) / G;
    const char* base = po + (size_t)(b * SPB + acc) * SLOT_BYTES;
    const int r0 = qtr * 32;

    if (tid < 32) {
        float v = 0.f;
        for (int sg = 0; sg < segs; ++sg)
            v += ((const float*)(base + (size_t)sg * SLOT_BYTES + SLOT_L_OFF))[r0 + tid];
        lsum[tid] = v;
    }
    __syncthreads();

    const int rsub = tid >> 4;
    const int cg   = tid & 15;
    float a[2][8];
    #pragma unroll
    for (int p = 0; p < 2; ++p)
        #pragma unroll
        for (int j = 0; j < 8; ++j) a[p][j] = 0.f;

    for (int sg = 0; sg < segs; ++sg) {
        const char* sb = base + (size_t)sg * SLOT_BYTES;
        #pragma unroll
        for (int p = 0; p < 2; ++p) {
            int row = r0 + rsub + p * 16;
            union { uint4 u; __bf16 h[8]; } v;
            v.u = *(const uint4*)(sb + ((size_t)row * 128 + cg * 8) * 2);
            #pragma unroll
            for (int j = 0; j < 8; ++j) a[p][j] += (float)v.h[j];
        }
    }

    #pragma unroll
    for (int p = 0; p < 2; ++p) {
        int row = r0 + rsub + p * 16;
        float inv = 1.0f / lsum[rsub + p * 16];
        float* op = outp + (size_t)(b * TT + qt * 128 + row) * HH + cg * 8;
        float4 o0 = {a[p][0] * inv, a[p][1] * inv, a[p][2] * inv, a[p][3] * inv};
        float4 o1 = {a[p][4] * inv, a[p][5] * inv, a[p][6] * inv, a[p][7] * inv};
        *(float4*)op = o0;
        *(float4*)(op + 4) = o1;
    }
}

extern "C" void kernel_launch(void* const* d_in, const int* in_sizes, int n_in,
                              void* d_out, int out_size, void* d_ws, size_t ws_size,
                              hipStream_t stream)
{
    const float* x  = (const float*)d_in[0];
    const float* Wq = (const float*)d_in[1];
    const float* Wk = (const float*)d_in[2];
    const float* Wv = (const float*)d_in[3];
    __bf16* ws = (__bf16*)d_ws;
    float* out = (float*)d_out;
    char* po   = (char*)d_ws + PARTIAL_OFF_BYTES;

    int G = 0, SPB = 0, direct = 1;
    const int cand[4] = {5, 6, 8, 16};
    for (int ci = 0; ci < 4; ++ci) {
        int g = cand[ci], spb = 0;
        for (int q = 0; q < NQT128; ++q) spb += (2 * (q + 1) + g - 1) / g;
        size_t need = PARTIAL_OFF_BYTES + (size_t)spb * BB * SLOT_BYTES;
        if (need <= ws_size) { G = g; SPB = spb; direct = 0; break; }
    }
    if (direct) { G = 2 * NQT128; SPB = NQT128; }

    wcvt_kernel<<<24, 256, 0, stream>>>(Wq, Wk, Wv, ws + WBF_OFF);
    proj_kernel<<<512, 256, 0, stream>>>(x, ws);
    attn_kernel<<<SPB * 16, 256, 0, stream>>>(ws, po, out, G, SPB, direct);
    if (!direct) {
        dim3 rgrid(NQT128 * 4, BB);
        reduce_kernel<<<rgrid, 256, 0, stream>>>(po, out, G, SPB);
    }
}

// Round 3
// 121.576 us; speedup vs baseline: 1.5872x; 1.5872x over previous
//
#include <hip/hip_runtime.h>
#include <hip/hip_bf16.h>

// Problem constants
#define BB 16
#define TT 2048
#define CC 128
#define HH 128
#define NQT128 16          // q tiles of 128 rows

typedef __bf16 bf16x8 __attribute__((ext_vector_type(8)));
typedef __bf16 bf16x4 __attribute__((ext_vector_type(4)));
typedef float  f32x4  __attribute__((ext_vector_type(4)));
typedef unsigned int u32x2 __attribute__((ext_vector_type(2)));

// ws layout (bf16 elems unless noted):
//   Qs  [b][tt16 128][ks 4][lane 64][j 8]   (exp2-domain scale folded)
//   Ks  [b][tt16 128][ks 4][lane 64][j 8]   (32-key tile = 8 KB contig)
//   Vs  [b][t32 64][h16 8][lane 64][j 8]    (32-key tile = 8 KB contig)
//   Wbf 3*128*128 FRAGMENT-SWIZZLED: [which][blk16 8][ks 4][lane 64][j 8]
//   partial slots: bf16 o[128*128] (32768 B) + float l[128] (512 B)
#define BTH       ((size_t)BB * TT * HH)
#define WBF_OFF   (3 * BTH)
#define PARTIAL_OFF_BYTES (3 * BTH * 2 + 3 * 128 * 128 * 2)
#define SLOT_BYTES 33280
#define SLOT_L_OFF 32768

static __device__ __forceinline__ bf16x8 load_cvt8(const float* p) {
    float4 a = *(const float4*)p;
    float4 b = *(const float4*)(p + 4);
    bf16x8 r;
    r[0] = (__bf16)a.x; r[1] = (__bf16)a.y; r[2] = (__bf16)a.z; r[3] = (__bf16)a.w;
    r[4] = (__bf16)b.x; r[5] = (__bf16)b.y; r[6] = (__bf16)b.z; r[7] = (__bf16)b.w;
    return r;
}

// async global->LDS, 16 B/lane: data lands at lds_base + lane*16
static __device__ __forceinline__ void load_lds16(const void* g, void* l) {
    __builtin_amdgcn_global_load_lds(
        (const __attribute__((address_space(1))) unsigned int*)g,
        (__attribute__((address_space(3))) unsigned int*)l, 16, 0, 0);
}

#define BAR_LGKM() asm volatile("s_waitcnt lgkmcnt(0)\n\ts_barrier" ::: "memory")

// ---------------------------------------------------------------------------
// W pre-convert + FRAGMENT SWIZZLE (proj W loads become lane*16B coalesced).
// ---------------------------------------------------------------------------
__global__ __launch_bounds__(256) void wcvt_kernel(
    const float* __restrict__ Wq, const float* __restrict__ Wk,
    const float* __restrict__ Wv, __bf16* __restrict__ wbf)
{
    int idx = blockIdx.x * 256 + threadIdx.x;          // < 6144
    int which = idx >> 11;
    int rem = idx & 2047;
    int blk = rem >> 8;
    int r2  = rem & 255;
    int ks   = r2 >> 6;
    int lane = r2 & 63;
    int quad = lane >> 4, l16 = lane & 15;
    const float* src = (which == 0) ? Wq : (which == 1) ? Wk : Wv;
    float sc = (which == 0) ? (0.08838834764831845f * 1.4426950408889634f) : 1.0f;
    const float* p = src + (size_t)(blk * 16 + l16) * CC + ks * 32 + quad * 8;
    bf16x8 v;
    #pragma unroll
    for (int j = 0; j < 8; ++j) v[j] = (__bf16)(p[j] * sc);
    *(bf16x8*)(wbf + (size_t)which * 16384 + (((size_t)(blk * 4 + ks)) << 9) + lane * 8) = v;
}

// ---------------------------------------------------------------------------
// Projection, fully coalesced (x via padded LDS, W fragment-swizzled).
// ---------------------------------------------------------------------------
#define TR_QK 132
#define TR_V  68

__global__ __launch_bounds__(256) void proj_kernel(
    const float* __restrict__ x, __bf16* __restrict__ ws)
{
    __shared__ float  xs[64 * 132];
    __shared__ __bf16 tr[128 * TR_V];

    const int lane = threadIdx.x & 63;
    const int wave = threadIdx.x >> 6;
    const int quad = lane >> 4;
    const int l16  = lane & 15;
    const int tid  = threadIdx.x;
    const int m0 = blockIdx.x * 64;
    const int b  = m0 / TT;
    const int t0 = m0 % TT;

    const __bf16* Wbf = ws + WBF_OFF;
    __bf16* Qs = ws;
    __bf16* Ks = ws + BTH;
    __bf16* Vs = ws + 2 * BTH;

    const float* xg = x + (size_t)m0 * CC;
    #pragma unroll
    for (int t = 0; t < 8; ++t) {
        int f = t * 256 + tid;
        int row = f >> 5, c4 = f & 31;
        float4 v = *(const float4*)(xg + (size_t)f * 4);
        *(float4*)(&xs[row * 132 + c4 * 4]) = v;
    }
    __syncthreads();

    bf16x8 xf[4];
    #pragma unroll
    for (int ks = 0; ks < 4; ++ks)
        xf[ks] = load_cvt8(&xs[(wave * 16 + l16) * 132 + ks * 32 + quad * 8]);

    #pragma unroll
    for (int which = 0; which < 2; ++which) {
        const __bf16* Wb = Wbf + (size_t)which * 16384;
        __bf16* dst = which ? Ks : Qs;
        #pragma unroll
        for (int nt = 0; nt < 8; ++nt) {
            f32x4 acc = {0.f, 0.f, 0.f, 0.f};
            #pragma unroll
            for (int ks = 0; ks < 4; ++ks) {
                bf16x8 wf = *(const bf16x8*)(Wb + (((size_t)(nt * 4 + ks)) << 9) + lane * 8);
                acc = __builtin_amdgcn_mfma_f32_16x16x32_bf16(xf[ks], wf, acc, 0, 0, 0);
            }
            #pragma unroll
            for (int r = 0; r < 4; ++r)
                tr[(wave * 16 + quad * 4 + r) * TR_QK + nt * 16 + l16] = (__bf16)acc[r];
        }
        asm volatile("s_waitcnt lgkmcnt(0)" ::: "memory");
        #pragma unroll
        for (int ks = 0; ks < 4; ++ks) {
            const __bf16* p = &tr[(wave * 16 + l16) * TR_QK + ks * 32 + quad * 8];
            uint2 lo = *(const uint2*)p;
            uint2 hi = *(const uint2*)(p + 4);
            uint4 v; v.x = lo.x; v.y = lo.y; v.z = hi.x; v.w = hi.y;
            __bf16* o = dst + (((size_t)(b * 128 + t0 / 16 + wave) * 4 + ks) << 9) + lane * 8;
            *(uint4*)o = v;
        }
        asm volatile("s_waitcnt lgkmcnt(0)" ::: "memory");
    }

    __syncthreads();
    const __bf16* Wv = Wbf + 2 * 16384;
    #pragma unroll
    for (int msub = 0; msub < 8; ++msub) {
        f32x4 acc = {0.f, 0.f, 0.f, 0.f};
        #pragma unroll
        for (int ks = 0; ks < 4; ++ks) {
            bf16x8 wf = *(const bf16x8*)(Wv + (((size_t)(msub * 4 + ks)) << 9) + lane * 8);
            acc = __builtin_amdgcn_mfma_f32_16x16x32_bf16(wf, xf[ks], acc, 0, 0, 0);
        }
        #pragma unroll
        for (int r = 0; r < 4; ++r)
            tr[(msub * 16 + quad * 4 + r) * TR_V + wave * 16 + l16] = (__bf16)acc[r];
    }
    __syncthreads();
    #pragma unroll
    for (int i = 0; i < 4; ++i) {
        int t32 = i >> 1;
        int h16 = wave * 2 + (i & 1);
        const __bf16* p = &tr[(h16 * 16 + l16) * TR_V + t32 * 32 + quad * 8];
        uint2 lo = *(const uint2*)p;
        uint2 hi = *(const uint2*)(p + 4);
        uint4 v; v.x = lo.x; v.y = lo.y; v.z = hi.x; v.w = hi.y;
        __bf16* o = Vs + (((size_t)(b * 64 + t0 / 32 + t32) * 8 + h16) << 9) + lane * 8;
        *(uint4*)o = v;
    }
}

// ---------------------------------------------------------------------------
// Split-K flash attention, 32-key tiles, double-buffered LDS staging.
//  - swapped QK^T (mfma(K,Q) -> S^T), then P redistribution ENTIRELY
//    IN-REGISTER: 1x permlane32_swap + 1x permlane16_swap per (m,h) moves
//    lane bits (q1,q0) -> (n,j1). No P LDS buffer, no mid-tile lgkm drain,
//    no bank conflicts from P traffic.
//  - counted vmcnt(4): next-tile DMA issued BEFORE the barrier, never drained
//    to 0 mid-loop (stage(t)'s 4 loads are oldest of exactly 8 outstanding).
//  - LDS 32768 B; plain __launch_bounds__(256) (the (256,4) variant forced a
//    64-VGPR cap -> accumulator spills -> 176 MB scratch traffic. Never again.)
// ---------------------------------------------------------------------------
__global__ __launch_bounds__(256) void attn_kernel(
    const __bf16* __restrict__ ws, char* __restrict__ po,
    float* __restrict__ outp, int G, int SPB, int direct)
{
    __shared__ __bf16 ldsK[2][4096];            // 2 x 8 KB
    __shared__ __bf16 ldsV[2][4096];            // 2 x 8 KB  -> total 32768 B

    const int lane = threadIdx.x & 63;
    const int wave = threadIdx.x >> 6;
    const int quad = lane >> 4;
    const int l16  = lane & 15;
    const int lane8 = lane * 8;
    const int lo16 = lane * 16;

    const int lin = blockIdx.x;
    const int b  = (lin & 7) * 2 + ((lin >> 3) & 1);   // XCD-clustered batch
    const int s  = SPB - 1 - (lin >> 4);               // heavy slots first

    // slot -> (qt, seg) in 64-key units, then convert to 32-key tiles
    int acc = 0, qt = 0, seg = 0;
    for (int q = 0; q < NQT128; ++q) {
        int c = (2 * (q + 1) + G - 1) / G;
        if (s < acc + c) { qt = q; seg = s - acc; break; }
        acc += c;
    }
    const int kt0 = seg * G;
    int kt1 = 2 * (qt + 1);
    if (kt0 + G < kt1) kt1 = kt0 + G;
    const int segs_qt = (2 * (qt + 1) + G - 1) / G;
    const int dwrite = direct | (segs_qt == 1);

    const int tt0 = kt0 * 2, tt1 = kt1 * 2;            // 32-key tiles (even count)
    const int qw = qt * 128 + wave * 32;               // wave's first q row
    int ttw = (qw + 63) >> 5;                          // wave causal clamp
    if (ttw > tt1) ttw = tt1;

    const __bf16* Qs = ws;
    const __bf16* Ks = ws + BTH;
    const __bf16* Vs = ws + 2 * BTH;

    bf16x8 qf[2][4];
    #pragma unroll
    for (int m = 0; m < 2; ++m)
        #pragma unroll
        for (int ks = 0; ks < 4; ++ks)
            qf[m][ks] = *(const bf16x8*)(Qs + (((size_t)(b * 128 + qt * 8 + wave * 2 + m) * 4 + ks) << 9) + lane8);

    float l_r[2] = {0.f, 0.f};
    f32x4 o[2][8];
    #pragma unroll
    for (int m = 0; m < 2; ++m)
        #pragma unroll
        for (int h8 = 0; h8 < 8; ++h8) o[m][h8] = (f32x4){0.f, 0.f, 0.f, 0.f};

    // incremental staging pointers: each 32-key tile is 8 KB contiguous
    const char* kg = (const char*)Ks + (size_t)b * 524288 + wave * 2048 + lo16;
    const char* vg = (const char*)Vs + (size_t)b * 524288 + wave * 2048 + lo16;
    char* const dKa[2] = {(char*)ldsK[0] + wave * 2048, (char*)ldsK[1] + wave * 2048};
    char* const dVa[2] = {(char*)ldsV[0] + wave * 2048, (char*)ldsV[1] + wave * 2048};

    #define STAGE(TTv, KD, VD)                                  \
        do {                                                    \
            size_t o_ = (size_t)(TTv) << 13;                    \
            load_lds16(kg + o_,        (KD));                   \
            load_lds16(kg + o_ + 1024, (KD) + 1024);            \
            load_lds16(vg + o_,        (VD));                   \
            load_lds16(vg + o_ + 1024, (VD) + 1024);            \
        } while (0)

    STAGE(tt0, dKa[0], dVa[0]);

    for (int tp = tt0; tp < tt1; tp += 2) {
        #pragma unroll
        for (int hh = 0; hh < 2; ++hh) {
            const int tt = tp + hh;
            // issue next-tile DMA before the barrier; counted wait keeps it in flight
            if (tt + 1 < tt1) {
                STAGE(tt + 1, dKa[hh ^ 1], dVa[hh ^ 1]);
                asm volatile("s_waitcnt vmcnt(4)" ::: "memory");
            } else {
                asm volatile("s_waitcnt vmcnt(0)" ::: "memory");
            }
            __builtin_amdgcn_s_barrier();

            if (tt < ttw) {
                const char* lk = (const char*)ldsK[hh];
                const char* lv = (const char*)ldsV[hh];

                // ---- S^T = K Q^T (swapped: lane holds 4 consecutive keys / q) --
                f32x4 s2[2][2];
                #pragma unroll
                for (int nsub = 0; nsub < 2; ++nsub) {
                    bf16x8 kfr[4];
                    #pragma unroll
                    for (int ks = 0; ks < 4; ++ks)
                        kfr[ks] = *(const bf16x8*)(lk + ((nsub * 4 + ks) << 10) + lo16);
                    #pragma unroll
                    for (int m = 0; m < 2; ++m) {
                        f32x4 a2 = {0.f, 0.f, 0.f, 0.f};
                        #pragma unroll
                        for (int ks = 0; ks < 4; ++ks)
                            a2 = __builtin_amdgcn_mfma_f32_16x16x32_bf16(kfr[ks], qf[m][ks], a2, 0, 0, 0);
                        s2[m][nsub] = a2;
                    }
                }

                const int k0 = tt * 32;
                // ---- mask + exp2 + lane-local l; pack P into dwords ----------
                // du[m][n][h] = bf16x2 of keys (n*16 + quad*4 + 2h, +2h+1), row l16
                unsigned int du[2][2][2];
                #pragma unroll
                for (int m = 0; m < 2; ++m) {
                    const int qrow = qw + m * 16 + l16;     // this lane's q row
                    if (k0 + 31 > qw + m * 16) {            // boundary tile (uniform)
                        #pragma unroll
                        for (int nsub = 0; nsub < 2; ++nsub) {
                            const int kb = k0 + nsub * 16 + quad * 4;
                            union { bf16x4 v; unsigned int u[2]; } cv;
                            #pragma unroll
                            for (int r = 0; r < 4; ++r) {
                                float sv = (kb + r > qrow) ? -3e38f : s2[m][nsub][r];
                                float p = __builtin_amdgcn_exp2f(sv);
                                l_r[m] += p;
                                cv.v[r] = (__bf16)p;
                            }
                            du[m][nsub][0] = cv.u[0];
                            du[m][nsub][1] = cv.u[1];
                        }
                    } else {
                        #pragma unroll
                        for (int nsub = 0; nsub < 2; ++nsub) {
                            union { bf16x4 v; unsigned int u[2]; } cv;
                            #pragma unroll
                            for (int r = 0; r < 4; ++r) {
                                float p = __builtin_amdgcn_exp2f(s2[m][nsub][r]);
                                l_r[m] += p;
                                cv.v[r] = (__bf16)p;
                            }
                            du[m][nsub][0] = cv.u[0];
                            du[m][nsub][1] = cv.u[1];
                        }
                    }
                }

                // ---- P: C-layout -> A-layout fully in-register ---------------
                // dst lane (q'1,q'0) dword j needs src lane (q1=q'0, q0=j1),
                // register (n=q'1, h=j0).
                // Step A: permlane32_swap moves register-bit n into lane bit 5.
                // Step B: permlane16_swap swaps lane bit 4 with register pair.
                bf16x8 pf[2];
                #pragma unroll
                for (int m = 0; m < 2; ++m) {
                    union { unsigned int u[4]; bf16x8 v; } cc;
                    #pragma unroll
                    for (int h = 0; h < 2; ++h) {
                        u32x2 t1 = __builtin_amdgcn_permlane32_swap(
                            du[m][0][h], du[m][1][h], false, false);
                        u32x2 t2 = __builtin_amdgcn_permlane16_swap(
                            t1[0], t1[1], false, false);
                        cc.u[h]     = t2[0];   // dword j = h     (q0_old=0)
                        cc.u[2 + h] = t2[1];   // dword j = 2 + h (q0_old=1)
                    }
                    pf[m] = cc.v;
                }

                // ---- O += P V (k = 32) ---------------------------------------
                #pragma unroll
                for (int h8 = 0; h8 < 8; ++h8) {
                    bf16x8 v0 = *(const bf16x8*)(lv + (h8 << 10) + lo16);
                    #pragma unroll
                    for (int m = 0; m < 2; ++m)
                        o[m][h8] = __builtin_amdgcn_mfma_f32_16x16x32_bf16(pf[m], v0, o[m][h8], 0, 0, 0);
                }
            }
            BAR_LGKM();    // all waves' LDS reads of buf hh complete before reuse
        }
    }
    #undef STAGE

    // l reduction across quads (row l16's sum becomes uniform over quads)
    #pragma unroll
    for (int m = 0; m < 2; ++m) {
        l_r[m] += __shfl_xor(l_r[m], 16, 64);
        l_r[m] += __shfl_xor(l_r[m], 32, 64);
    }

    if (dwrite) {
        #pragma unroll
        for (int m = 0; m < 2; ++m) {
            float inv[4];
            #pragma unroll
            for (int r = 0; r < 4; ++r)
                inv[r] = 1.0f / __shfl(l_r[m], (lane & 48) | (quad * 4 + r), 64);
            #pragma unroll
            for (int h8 = 0; h8 < 8; ++h8)
                #pragma unroll
                for (int r = 0; r < 4; ++r)
                    outp[(size_t)(b * TT + qw + m * 16 + quad * 4 + r) * HH + h8 * 16 + l16] = o[m][h8][r] * inv[r];
        }
    } else {
        char* slot = po + (size_t)(b * SPB + s) * SLOT_BYTES;
        __bf16* slot_o = (__bf16*)slot;
        float*  slot_l = (float*)(slot + SLOT_L_OFF);
        #pragma unroll
        for (int m = 0; m < 2; ++m) {
            #pragma unroll
            for (int h8 = 0; h8 < 8; ++h8)
                #pragma unroll
                for (int r = 0; r < 4; ++r)
                    slot_o[(size_t)(wave * 32 + m * 16 + quad * 4 + r) * 128 + h8 * 16 + l16] = (__bf16)o[m][h8][r];
            if (quad == 0)
                slot_l[wave * 32 + m * 16 + l16] = l_r[m];
        }
    }
}

// ---------------------------------------------------------------------------
// Reduce: sum bf16 partial o + fp32 l over segments, normalize.
// ---------------------------------------------------------------------------
__global__ __launch_bounds__(256) void reduce_kernel(
    const char* __restrict__ po, float* __restrict__ outp, int G, int SPB)
{
    __shared__ float lsum[32];
    const int qt  = blockIdx.x >> 2;
    const int qtr = blockIdx.x & 3;
    const int b   = blockIdx.y;
    const int tid = threadIdx.x;

    const int segs = (2 * (qt + 1) + G - 1) / G;
    if (segs == 1) return;

    int acc = 0;
    for (int qq = 0; qq < qt; ++qq) acc += (2 * (qq + 1) + G - 1) / G;
    const char* base = po + (size_t)(b * SPB + acc) * SLOT_BYTES;
    const int r0 = qtr * 32;

    if (tid < 32) {
        float v = 0.f;
        for (int sg = 0; sg < segs; ++sg)
            v += ((const float*)(base + (size_t)sg * SLOT_BYTES + SLOT_L_OFF))[r0 + tid];
        lsum[tid] = v;
    }
    __syncthreads();

    const int rsub = tid >> 4;
    const int cg   = tid & 15;
    float a[2][8];
    #pragma unroll
    for (int p = 0; p < 2; ++p)
        #pragma unroll
        for (int j = 0; j < 8; ++j) a[p][j] = 0.f;

    for (int sg = 0; sg < segs; ++sg) {
        const char* sb = base + (size_t)sg * SLOT_BYTES;
        #pragma unroll
        for (int p = 0; p < 2; ++p) {
            int row = r0 + rsub + p * 16;
            union { uint4 u; __bf16 h[8]; } v;
            v.u = *(const uint4*)(sb + ((size_t)row * 128 + cg * 8) * 2);
            #pragma unroll
            for (int j = 0; j < 8; ++j) a[p][j] += (float)v.h[j];
        }
    }

    #pragma unroll
    for (int p = 0; p < 2; ++p) {
        int row = r0 + rsub + p * 16;
        float inv = 1.0f / lsum[rsub + p * 16];
        float* op = outp + (size_t)(b * TT + qt * 128 + row) * HH + cg * 8;
        float4 o0 = {a[p][0] * inv, a[p][1] * inv, a[p][2] * inv, a[p][3] * inv};
        float4 o1 = {a[p][4] * inv, a[p][5] * inv, a[p][6] * inv, a[p][7] * inv};
        *(float4*)op = o0;
        *(float4*)(op + 4) = o1;
    }
}

extern "C" void kernel_launch(void* const* d_in, const int* in_sizes, int n_in,
                              void* d_out, int out_size, void* d_ws, size_t ws_size,
                              hipStream_t stream)
{
    const float* x  = (const float*)d_in[0];
    const float* Wq = (const float*)d_in[1];
    const float* Wk = (const float*)d_in[2];
    const float* Wv = (const float*)d_in[3];
    __bf16* ws = (__bf16*)d_ws;
    float* out = (float*)d_out;
    char* po   = (char*)d_ws + PARTIAL_OFF_BYTES;

    int G = 0, SPB = 0, direct = 1;
    const int cand[4] = {5, 6, 8, 16};
    for (int ci = 0; ci < 4; ++ci) {
        int g = cand[ci], spb = 0;
        for (int q = 0; q < NQT128; ++q) spb += (2 * (q + 1) + g - 1) / g;
        size_t need = PARTIAL_OFF_BYTES + (size_t)spb * BB * SLOT_BYTES;
        if (need <= ws_size) { G = g; SPB = spb; direct = 0; break; }
    }
    if (direct) { G = 2 * NQT128; SPB = NQT128; }

    wcvt_kernel<<<24, 256, 0, stream>>>(Wq, Wk, Wv, ws + WBF_OFF);
    proj_kernel<<<512, 256, 0, stream>>>(x, ws);
    attn_kernel<<<SPB * 16, 256, 0, stream>>>(ws, po, out, G, SPB, direct);
    if (!direct) {
        dim3 rgrid(NQT128 * 4, BB);
        reduce_kernel<<<rgrid, 256, 0, stream>>>(po, out, G, SPB);
    }
}